// Round 10
// baseline (561.616 us; speedup 1.0000x reference)
//
#include <hip/hip_runtime.h>
#include <math.h>

// Problem constants
#define N_TOK 131072   // 32*64*64 tokens
#define D     64       // embedding dim
#define K     1024     // codebook size

// Output layout (floats, concatenated in reference return order):
#define OUT_LOSS  8388608
#define OUT_IDX   8388609
#define OUT_PERP  8519681

// ws layout (bytes):
//   0        counts  u32[1024]
//   4096     enorm   f32[1024]  np-exact ||e||^2
//   8192     sinit   f32[1024]  fp64-accurate ||e||^2 (screen C-init)
//   12288    sse     f32
//   12292    rcnt    u32        rescue-list counter
//   16384    w_hi    s16[65536] bf16 hi split of w (128 KB)
//   147456   w_lo    s16[65536] bf16 lo split of w (128 KB)
//   278528   win     i32[131072] packed winner (bit31 = needs rescue)
//   802816   rlist   i32[131072] compacted rescue token ids (512 KB)
//   1327104  wt      f32[64][1024] transposed codebook (256 KB)

#define W_WINDOW 1e-4f

typedef short bf16x8 __attribute__((ext_vector_type(8)));
typedef float f32x4  __attribute__((ext_vector_type(4)));

// LDS byte-offset swizzle: XOR bits 4-6 with row bits (byte>>7)&7.
// Involution; applied on BOTH ds_write (staging) and ds_read (fragments).
#define SWZ(p) ((p) ^ ((((p) >> 7) & 7) << 4))

__device__ __forceinline__ short bf16_trunc(float f) {
    return (short)(__float_as_uint(f) >> 16);
}
__device__ __forceinline__ float bf16_up(short s) {
    return __uint_as_float(((unsigned)(unsigned short)s) << 16);
}

// float -> order-preserving u32 (ascending)
__device__ __forceinline__ unsigned fsort(float f) {
    unsigned u = __float_as_uint(f);
    return (u & 0x80000000u) ? ~u : (u | 0x80000000u);
}

// ---------------------------------------------------------------------------
// prep v3: lane<->dim layout, fully coalesced; bit-exact enorm/sinit orders.
// Adds the wt transpose (wt[d][c] = w[c][d]) for the lane=code rescue.
// ---------------------------------------------------------------------------
__global__ __launch_bounds__(256, 4)
void vq_prep(const float* __restrict__ w,
             float* __restrict__ enorm,
             float* __restrict__ sinit,
             short* __restrict__ w_hi,
             short* __restrict__ w_lo,
             float* __restrict__ wt,
             unsigned* __restrict__ counts,
             float* __restrict__ sse,
             unsigned* __restrict__ rcnt) {
    const int lane = threadIdx.x & 63;
    const int wv   = threadIdx.x >> 6;
    const int gw   = blockIdx.x * 4 + wv;        // global wave 0..255

#pragma unroll
    for (int rr = 0; rr < 4; ++rr) {
        const int k = gw * 4 + rr;               // row 0..1023
        const float v = w[(size_t)k * D + lane]; // coalesced 256B

        short hi = bf16_trunc(v);
        float res = v - bf16_up(hi);
        short lo = bf16_trunc(res);
        w_hi[(size_t)k * D + lane] = hi;         // coalesced
        w_lo[(size_t)k * D + lane] = lo;
        wt[(size_t)lane * K + k] = v;            // transpose (scattered, tiny)

        // enorm: np_pairsum64 exact order.
        const float s = __fmul_rn(v, v);
        float r = s;                             // lanes 0..7 start at sq[j]
#pragma unroll
        for (int i = 1; i < 8; ++i)
            r = __fadd_rn(r, __shfl(s, i * 8 + (lane & 7), 64));
        float t01 = __fadd_rn(__shfl(r, 0, 64), __shfl(r, 1, 64));
        float t23 = __fadd_rn(__shfl(r, 2, 64), __shfl(r, 3, 64));
        float t45 = __fadd_rn(__shfl(r, 4, 64), __shfl(r, 5, 64));
        float t67 = __fadd_rn(__shfl(r, 6, 64), __shfl(r, 7, 64));
        float en  = __fadd_rn(__fadd_rn(t01, t23), __fadd_rn(t45, t67));

        // sinit: exact sequential fp64 order (0+d0)+d1+...+d63.
        double dq = (double)v * (double)v;
        double acc = __shfl(dq, 0, 64);
#pragma unroll
        for (int d2 = 1; d2 < 64; ++d2)
            acc = acc + __shfl(dq, d2, 64);

        if (lane == 0) {
            enorm[k] = en;
            sinit[k] = (float)acc;
            counts[k] = 0u;
        }
    }
    if (blockIdx.x == 0 && threadIdx.x == 0) { *sse = 0.f; *rcnt = 0u; }
}

// ---------------------------------------------------------------------------
// Screen (round-5 structure, 66 us verified): LDS-staged codebook chunks
// (double-buffered, swizzled), 12-MFMA hi/lo scheme, in-register top-2,
// packed winner to win[]. sinit staged to LDS once.
// ---------------------------------------------------------------------------
#define MFMA(A, B, C) __builtin_amdgcn_mfma_f32_16x16x32_bf16(A, B, C, 0, 0, 0)

__device__ __forceinline__ void tile_step(
    int code, const bf16x8 (&Ah)[2][2], const bf16x8 (&Al)[2][2],
    bf16x8 H0, bf16x8 H1, bf16x8 L0, bf16x8 L1, float si,
    float (&m1)[8], float (&m2)[8], int (&i1)[8]) {
    f32x4 C0 = {si, si, si, si};
    f32x4 C1 = {si, si, si, si};
    C0 = MFMA(Ah[0][0], H0, C0); C0 = MFMA(Ah[0][1], H1, C0);
    C0 = MFMA(Ah[0][0], L0, C0); C0 = MFMA(Ah[0][1], L1, C0);
    C0 = MFMA(Al[0][0], H0, C0); C0 = MFMA(Al[0][1], H1, C0);
    C1 = MFMA(Ah[1][0], H0, C1); C1 = MFMA(Ah[1][1], H1, C1);
    C1 = MFMA(Ah[1][0], L0, C1); C1 = MFMA(Ah[1][1], L1, C1);
    C1 = MFMA(Al[1][0], H0, C1); C1 = MFMA(Al[1][1], H1, C1);
#pragma unroll
    for (int r = 0; r < 4; ++r) {
        {
            float c = C0[r];
            // med3(m1,m2,c) == min(m2, max(m1,c)) given m1<=m2 (exact select)
            m2[r] = __builtin_amdgcn_fmed3f(m1[r], m2[r], c);
            bool lt = c < m1[r];
            i1[r] = lt ? code : i1[r];
            m1[r] = fminf(m1[r], c);
        }
        {
            float c = C1[r];
            m2[4 + r] = __builtin_amdgcn_fmed3f(m1[4 + r], m2[4 + r], c);
            bool lt = c < m1[4 + r];
            i1[4 + r] = lt ? code : i1[4 + r];
            m1[4 + r] = fminf(m1[4 + r], c);
        }
    }
}

__global__ __launch_bounds__(256, 4)
void vq_screen(const float* __restrict__ x,
               const float* __restrict__ sinit,
               const short* __restrict__ w_hi,
               const short* __restrict__ w_lo,
               int* __restrict__ win) {
    const int tid  = threadIdx.x;
    const int lane = tid & 63;
    const int wv   = __builtin_amdgcn_readfirstlane(tid >> 6);
    const int quad = lane >> 4;
    const int col  = lane & 15;
    const int tokWave = blockIdx.x * 128 + wv * 32;

    // [buf][hi/lo][64 codes * 64 dims] = 32 KB
    __shared__ short sB[2][2][4096];
    __shared__ float sS[1024];   // sinit staged once (4 KB)

    bf16x8 Ah[2][2], Al[2][2];
#pragma unroll
    for (int mt = 0; mt < 2; ++mt) {
#pragma unroll
        for (int ks = 0; ks < 2; ++ks) {
            const float4* ap = (const float4*)(x + (size_t)(tokWave + mt * 16 + col) * D
                                               + ks * 32 + quad * 8);
            float4 u0 = ap[0], u1 = ap[1];
            float f[8] = {u0.x, u0.y, u0.z, u0.w, u1.x, u1.y, u1.z, u1.w};
            bf16x8 h, l;
#pragma unroll
            for (int j = 0; j < 8; ++j) {
                float v = -2.0f * f[j];
                short hi = bf16_trunc(v);
                float res = v - bf16_up(hi);
                h[j] = hi;
                l[j] = bf16_trunc(res);
            }
            Ah[mt][ks] = h;
            Al[mt][ks] = l;
        }
    }

    float m1[8], m2[8];
    int   i1[8];
#pragma unroll
    for (int s = 0; s < 8; ++s) { m1[s] = INFINITY; m2[s] = INFINITY; i1[s] = 0; }

    // Staging geometry: chunk = 64 codes = 8192 B per array (hi, lo).
    const int  p0 = tid * 16;
    const int  p1 = p0 + 4096;
    const char* gh = (const char*)w_hi;
    const char* gl = (const char*)w_lo;

    // Initial stage: chunk 0 -> buf 0, plus sinit -> LDS.
    {
        float4 g0 = *(const float4*)(gh + p0);
        float4 g1 = *(const float4*)(gh + p1);
        float4 g2 = *(const float4*)(gl + p0);
        float4 g3 = *(const float4*)(gl + p1);
        float4 s4 = *(const float4*)(sinit + tid * 4);
        char* lh = (char*)&sB[0][0][0];
        char* ll = (char*)&sB[0][1][0];
        *(float4*)(lh + SWZ(p0)) = g0;
        *(float4*)(lh + SWZ(p1)) = g1;
        *(float4*)(ll + SWZ(p0)) = g2;
        *(float4*)(ll + SWZ(p1)) = g3;
        *(float4*)(&sS[tid * 4]) = s4;
    }
    __syncthreads();

    for (int c = 0; c < 16; ++c) {
        const int buf = c & 1;
        const bool pf = (c < 15);
        float4 g0, g1, g2, g3;
        if (pf) {
            const size_t cb = (size_t)(c + 1) * 8192;
            g0 = *(const float4*)(gh + cb + p0);
            g1 = *(const float4*)(gh + cb + p1);
            g2 = *(const float4*)(gl + cb + p0);
            g3 = *(const float4*)(gl + cb + p1);
        }

        const char* lh = (const char*)&sB[buf][0][0];
        const char* ll = (const char*)&sB[buf][1][0];
#pragma unroll
        for (int tl = 0; tl < 4; ++tl) {
            const int r_ = tl * 16 + col;          // code row within chunk
            const int b0 = r_ * 128 + quad * 16;
            const int b1 = b0 + 64;
            bf16x8 H0 = *(const bf16x8*)(lh + SWZ(b0));
            bf16x8 H1 = *(const bf16x8*)(lh + SWZ(b1));
            bf16x8 L0 = *(const bf16x8*)(ll + SWZ(b0));
            bf16x8 L1 = *(const bf16x8*)(ll + SWZ(b1));
            const int tile = c * 4 + tl;
            const float si = sS[tile * 16 + col];
            tile_step(tile * 16 + col, Ah, Al, H0, H1, L0, L1, si, m1, m2, i1);
        }

        if (pf) {
            char* dh = (char*)&sB[buf ^ 1][0][0];
            char* dl = (char*)&sB[buf ^ 1][1][0];
            *(float4*)(dh + SWZ(p0)) = g0;
            *(float4*)(dh + SWZ(p1)) = g1;
            *(float4*)(dl + SWZ(p0)) = g2;
            *(float4*)(dl + SWZ(p1)) = g3;
        }
        __syncthreads();
    }

#pragma unroll
    for (int s = 0; s < 8; ++s) {
#pragma unroll
        for (int msk = 1; msk <= 8; msk <<= 1) {
            float om1 = __shfl_xor(m1[s], msk, 64);
            int   oi1 = __shfl_xor(i1[s], msk, 64);
            float om2 = __shfl_xor(m2[s], msk, 64);
            float nm2 = fminf(fmaxf(m1[s], om1), fminf(m2[s], om2));
            bool  take = om1 < m1[s];
            m1[s] = take ? om1 : m1[s];
            i1[s] = take ? oi1 : i1[s];
            m2[s] = nm2;
        }
    }

    if (col == 0) {
#pragma unroll
        for (int s = 0; s < 8; ++s) {
            int tl = (s >> 2) * 16 + quad * 4 + (s & 3);
            bool resc = (m2[s] <= m1[s] + W_WINDOW);
            win[tokWave + tl] = resc ? (i1[s] | 0x80000000) : i1[s];
        }
    }
}
#undef MFMA

// ---------------------------------------------------------------------------
// Epilogue (r8 structure, no pk): phase A 1 thread/token into LDS winner
// table; phase B 16-lane/token coalesced gather+copy+SSE. 1024 blocks.
// ---------------------------------------------------------------------------
__global__ __launch_bounds__(256, 4)
void vq_epi(const float* __restrict__ x,
            const float* __restrict__ w,
            const int* __restrict__ win,
            float* __restrict__ out,
            unsigned* __restrict__ counts,
            float* __restrict__ sse,
            int* __restrict__ rlist,
            unsigned* __restrict__ rcnt) {
    __shared__ int smw[128];
    const int tb = blockIdx.x * 128;

    if (threadIdx.x < 128) {
        const int tok = tb + threadIdx.x;
        const int wi = win[tok];
        int v;
        if (wi < 0) {
            unsigned u = atomicAdd(rcnt, 1u);
            rlist[u] = tok;
            v = -1;
        } else {
            atomicAdd(&counts[wi], 1u);
            out[OUT_IDX + tok] = (float)wi;
            v = wi;
        }
        smw[threadIdx.x] = v;
    }
    __syncthreads();

    const int lane = threadIdx.x & 63;
    const int wvi  = threadIdx.x >> 6;
    const int sub  = lane >> 4;         // token within 4-token pass
    const int fi   = lane & 15;         // float4 index within 64-float row
    float err = 0.f;
#pragma unroll
    for (int p = 0; p < 8; ++p) {
        const int tl  = wvi * 32 + p * 4 + sub;          // local token 0..127
        const int tok = tb + tl;
        const int wi2 = smw[tl];
        if (wi2 >= 0) {
            float4 q  = ((const float4*)(w + (size_t)wi2 * D))[fi];
            float4 xv = ((const float4*)(x + (size_t)tok * D))[fi];
            float e0 = q.x - xv.x, e1 = q.y - xv.y;
            float e2 = q.z - xv.z, e3 = q.w - xv.w;
            err = fmaf(e0, e0, err);
            err = fmaf(e1, e1, err);
            err = fmaf(e2, e2, err);
            err = fmaf(e3, e3, err);
            ((float4*)(out + (size_t)tok * D))[fi] = q;
        }
    }
#pragma unroll
    for (int o = 32; o > 0; o >>= 1) err += __shfl_down(err, o, 64);
    if (lane == 0) atomicAdd(sse, err);
}

// ---------------------------------------------------------------------------
// Rescue v6 — lane=code geometry. Prior rescues died on w delivery
// (r8: s_load scalar-cache thrash, SGPR=112; r9: shfl=ds_bpermute LDS-pipe
// storm). Now: wave owns 8 tokens x ALL 1024 codes. Per d-step ONE coalesced
// vector load wt[d][c0+lane] + broadcast LDS reads of x (wave-uniform addr,
// free) + 8 independent fma chains (issue-bound). Per-(t,c) arithmetic
// bit-identical: single-acc fmaf chain d=0..63 ascending, same Sx sequence,
// same dist expression. First-min via u64 key (fsort(dist)<<32)|c minimized
// per-lane then cross-lane == np.argmin. Wave sees all codes -> commits its
// tokens directly: pk and the rfin kernel are gone.
// ---------------------------------------------------------------------------
__global__ __launch_bounds__(256, 4)
void vq_rescue(const float* __restrict__ x,
               const float* __restrict__ w,
               const float* __restrict__ wt,
               const float* __restrict__ enorm,
               float* __restrict__ out,
               unsigned* __restrict__ counts,
               float* __restrict__ sse,
               const int* __restrict__ rlist,
               const unsigned* __restrict__ rcnt) {
    const int lane = threadIdx.x & 63;
    const int wv   = threadIdx.x >> 6;           // 0..3
    const unsigned n = *rcnt;

    __shared__ float xs[4][8][65];               // padded token rows per wave
    __shared__ int   swin[4][8];

    for (unsigned slot = blockIdx.x * 4u + (unsigned)wv; slot * 8u < n;
         slot += 2048u) {
        const unsigned base = slot * 8u;

        // token ids: lane j<8 holds token j (dummy = rlist[base], base<n).
        int tj = 0;
        if (lane < 8) {
            const unsigned s2 = base + (unsigned)lane;
            tj = rlist[s2 < n ? s2 : base];
        }

        // stage 8 token rows into padded LDS (16 lanes/row, 2 sweeps)
#pragma unroll
        for (int it = 0; it < 2; ++it) {
            const int r  = it * 4 + (lane >> 4);
            const int fi = lane & 15;
            const int tr = __shfl(tj, r, 64);
            const float4 xv = ((const float4*)(x + (size_t)tr * D))[fi];
            float* dst = &xs[wv][r][fi * 4];
            dst[0] = xv.x; dst[1] = xv.y; dst[2] = xv.z; dst[3] = xv.w;
        }

        // Sx per token (lane j<8 -> token j), exact 8-acc + pairwise order.
        float Sx = 0.f;
        if (lane < 8) {
            const float* xr = &xs[wv][lane][0];
#define SQw(i) __fmul_rn(xr[i], xr[i])
            float r0 = SQw(0), r1 = SQw(1), r2 = SQw(2), r3 = SQw(3);
            float r4 = SQw(4), r5 = SQw(5), r6 = SQw(6), r7 = SQw(7);
#pragma unroll
            for (int i = 1; i < 8; ++i) {
                r0 = __fadd_rn(r0, SQw(8 * i + 0));
                r1 = __fadd_rn(r1, SQw(8 * i + 1));
                r2 = __fadd_rn(r2, SQw(8 * i + 2));
                r3 = __fadd_rn(r3, SQw(8 * i + 3));
                r4 = __fadd_rn(r4, SQw(8 * i + 4));
                r5 = __fadd_rn(r5, SQw(8 * i + 5));
                r6 = __fadd_rn(r6, SQw(8 * i + 6));
                r7 = __fadd_rn(r7, SQw(8 * i + 7));
            }
#undef SQw
            Sx = __fadd_rn(
                __fadd_rn(__fadd_rn(r0, r1), __fadd_rn(r2, r3)),
                __fadd_rn(__fadd_rn(r4, r5), __fadd_rn(r6, r7)));
        }
        const float Sb0 = __shfl(Sx, 0, 64), Sb1 = __shfl(Sx, 1, 64);
        const float Sb2 = __shfl(Sx, 2, 64), Sb3 = __shfl(Sx, 3, 64);
        const float Sb4 = __shfl(Sx, 4, 64), Sb5 = __shfl(Sx, 5, 64);
        const float Sb6 = __shfl(Sx, 6, 64), Sb7 = __shfl(Sx, 7, 64);

        unsigned long long k0 = ~0ull, k1 = ~0ull, k2 = ~0ull, k3 = ~0ull;
        unsigned long long k4 = ~0ull, k5 = ~0ull, k6 = ~0ull, k7 = ~0ull;

        for (int p = 0; p < 16; ++p) {
            const int c = p * 64 + lane;
            const float en = enorm[c];
            const float* wp = wt + p * 64 + lane;
            const float* xw = &xs[wv][0][0];
            float a0 = 0.f, a1 = 0.f, a2 = 0.f, a3 = 0.f;
            float a4 = 0.f, a5 = 0.f, a6 = 0.f, a7 = 0.f;
#pragma unroll 8
            for (int d = 0; d < 64; ++d) {
                const float wvv = wp[(size_t)d << 10];  // coalesced 256B/wave
                a0 = __fmaf_rn(wvv, xw[0 * 65 + d], a0);
                a1 = __fmaf_rn(wvv, xw[1 * 65 + d], a1);
                a2 = __fmaf_rn(wvv, xw[2 * 65 + d], a2);
                a3 = __fmaf_rn(wvv, xw[3 * 65 + d], a3);
                a4 = __fmaf_rn(wvv, xw[4 * 65 + d], a4);
                a5 = __fmaf_rn(wvv, xw[5 * 65 + d], a5);
                a6 = __fmaf_rn(wvv, xw[6 * 65 + d], a6);
                a7 = __fmaf_rn(wvv, xw[7 * 65 + d], a7);
            }
#define UPD(J)                                                                \
            {                                                                 \
                float dist = __fsub_rn(__fadd_rn(Sb##J, en),                  \
                                       __fmul_rn(2.0f, a##J));                \
                unsigned long long kk =                                       \
                    ((unsigned long long)fsort(dist) << 32) | (unsigned)c;    \
                k##J = kk < k##J ? kk : k##J;                                 \
            }
            UPD(0) UPD(1) UPD(2) UPD(3) UPD(4) UPD(5) UPD(6) UPD(7)
#undef UPD
        }

        // cross-lane first-min per token -> swin
#define RED(J)                                                                \
        {                                                                     \
            unsigned long long v_ = k##J;                                     \
            for (int m_ = 1; m_ < 64; m_ <<= 1) {                             \
                unsigned long long o_ = __shfl_xor(v_, m_, 64);               \
                v_ = o_ < v_ ? o_ : v_;                                       \
            }                                                                 \
            if (lane == 0) swin[wv][J] = (int)(v_ & 0xFFFFFFFFull);           \
        }
        RED(0) RED(1) RED(2) RED(3) RED(4) RED(5) RED(6) RED(7)
#undef RED

        // commit: 16 lanes/token, 4 tokens per sweep, 2 sweeps
        float err = 0.f;
#pragma unroll
        for (int g = 0; g < 2; ++g) {
            const int j  = g * 4 + (lane >> 4);
            const int fi = lane & 15;
            const int t  = __shfl(tj, j, 64);
            const bool v = (base + (unsigned)j) < n;
            if (v) {
                const int bi = swin[wv][j];
                float4 q = ((const float4*)(w + (size_t)bi * D))[fi];
                const float* xr = &xs[wv][j][fi * 4];
                float e0 = q.x - xr[0], e1 = q.y - xr[1];
                float e2 = q.z - xr[2], e3 = q.w - xr[3];
                err = fmaf(e0, e0, err);
                err = fmaf(e1, e1, err);
                err = fmaf(e2, e2, err);
                err = fmaf(e3, e3, err);
                ((float4*)(out + (size_t)t * D))[fi] = q;
                if (fi == 0) {
                    atomicAdd(&counts[bi], 1u);
                    out[OUT_IDX + t] = (float)bi;
                }
            }
        }
#pragma unroll
        for (int o = 32; o > 0; o >>= 1) err += __shfl_down(err, o, 64);
        if (lane == 0 && err != 0.f) atomicAdd(sse, err);
    }
}

// ---------------------------------------------------------------------------
__global__ void vq_fin(const unsigned* __restrict__ counts,
                       const float* __restrict__ sse,
                       float* __restrict__ out) {
    __shared__ float red[256];
    float s = 0.f;
    for (int k = threadIdx.x; k < K; k += 256) {
        float p = (float)counts[k] * (1.0f / (float)N_TOK);
        s += p * logf(p + 1e-10f);
    }
    red[threadIdx.x] = s;
    __syncthreads();
    for (int st = 128; st > 0; st >>= 1) {
        if (threadIdx.x < st) red[threadIdx.x] += red[threadIdx.x + st];
        __syncthreads();
    }
    if (threadIdx.x == 0) {
        out[OUT_PERP] = expf(-red[0]);
        out[OUT_LOSS] = 1.25f * (*sse) * (1.0f / 8388608.0f);  // (1+0.25)*MSE
    }
}

// ---------------------------------------------------------------------------
extern "C" void kernel_launch(void* const* d_in, const int* in_sizes, int n_in,
                              void* d_out, int out_size, void* d_ws, size_t ws_size,
                              hipStream_t stream) {
    const float* x = (const float*)d_in[0];  // [32,64,64,64] fp32
    const float* w = (const float*)d_in[1];  // [1024,64] fp32
    float* out = (float*)d_out;

    char* ws = (char*)d_ws;
    unsigned* counts = (unsigned*)(ws + 0);
    float*    enorm  = (float*)(ws + 4096);
    float*    sinit  = (float*)(ws + 8192);
    float*    sse    = (float*)(ws + 12288);
    unsigned* rcnt   = (unsigned*)(ws + 12292);
    short*    w_hi   = (short*)(ws + 16384);
    short*    w_lo   = (short*)(ws + 147456);
    int*      win    = (int*)(ws + 278528);
    int*      rlist  = (int*)(ws + 802816);
    float*    wt     = (float*)(ws + 1327104);

    vq_prep<<<64, 256, 0, stream>>>(w, enorm, sinit, w_hi, w_lo, wt, counts,
                                    sse, rcnt);
    vq_screen<<<N_TOK / 128, 256, 0, stream>>>(x, sinit, w_hi, w_lo, win);
    vq_epi<<<N_TOK / 128, 256, 0, stream>>>(x, w, win, out, counts, sse,
                                            rlist, rcnt);
    vq_rescue<<<512, 256, 0, stream>>>(x, w, wt, enorm, out, counts, sse,
                                       rlist, rcnt);
    vq_fin<<<1, 256, 0, stream>>>(counts, sse, out);
}

// Round 11
// 278.055 us; speedup vs baseline: 2.0198x; 2.0198x over previous
//
#include <hip/hip_runtime.h>
#include <math.h>

// Problem constants
#define N_TOK 131072   // 32*64*64 tokens
#define D     64       // embedding dim
#define K     1024     // codebook size

// Output layout (floats, concatenated in reference return order):
#define OUT_LOSS  8388608
#define OUT_IDX   8388609
#define OUT_PERP  8519681

// ws layout (bytes):
//   0        counts  u32[1024]
//   4096     enorm   f32[1024]  np-exact ||e||^2
//   8192     sinit   f32[1024]  fp64-accurate ||e||^2 (screen C-init)
//   12288    sse     f32
//   12292    rcnt    u32        rescue-list counter
//   16384    w_hi    s16[65536] bf16 hi split of w (128 KB)
//   147456   w_lo    s16[65536] bf16 lo split of w (128 KB)
//   278528   win     i32[131072] packed winner (bit31 = needs rescue)
//   802816   rlist   i32[131072] compacted rescue token ids

#define W_WINDOW 1e-4f

typedef short bf16x8 __attribute__((ext_vector_type(8)));
typedef float f32x4  __attribute__((ext_vector_type(4)));
typedef float vf16   __attribute__((ext_vector_type(16)));

// LDS byte-offset swizzle: XOR bits 4-6 with row bits (byte>>7)&7.
// Involution; applied on BOTH ds_write (staging) and ds_read (fragments).
#define SWZ(p) ((p) ^ ((((p) >> 7) & 7) << 4))

__device__ __forceinline__ short bf16_trunc(float f) {
    return (short)(__float_as_uint(f) >> 16);
}
__device__ __forceinline__ float bf16_up(short s) {
    return __uint_as_float(((unsigned)(unsigned short)s) << 16);
}

// ---------------------------------------------------------------------------
// prep v2 (no wt transpose): lane<->dim layout, fully coalesced; bit-exact
// enorm (np_pairsum64 order via shfl) and sinit (sequential fp64 order).
// The ONLY change vs the proven 249-us r5 pipeline.
// ---------------------------------------------------------------------------
__global__ __launch_bounds__(256, 4)
void vq_prep(const float* __restrict__ w,
             float* __restrict__ enorm,
             float* __restrict__ sinit,
             short* __restrict__ w_hi,
             short* __restrict__ w_lo,
             unsigned* __restrict__ counts,
             float* __restrict__ sse,
             unsigned* __restrict__ rcnt) {
    const int lane = threadIdx.x & 63;
    const int wv   = threadIdx.x >> 6;
    const int gw   = blockIdx.x * 4 + wv;        // global wave 0..255

#pragma unroll
    for (int rr = 0; rr < 4; ++rr) {
        const int k = gw * 4 + rr;               // row 0..1023
        const float v = w[(size_t)k * D + lane]; // coalesced 256B

        short hi = bf16_trunc(v);
        float res = v - bf16_up(hi);
        short lo = bf16_trunc(res);
        w_hi[(size_t)k * D + lane] = hi;         // coalesced
        w_lo[(size_t)k * D + lane] = lo;

        // enorm: np_pairsum64 exact order.
        const float s = __fmul_rn(v, v);
        float r = s;                             // lanes 0..7 start at sq[j]
#pragma unroll
        for (int i = 1; i < 8; ++i)
            r = __fadd_rn(r, __shfl(s, i * 8 + (lane & 7), 64));
        float t01 = __fadd_rn(__shfl(r, 0, 64), __shfl(r, 1, 64));
        float t23 = __fadd_rn(__shfl(r, 2, 64), __shfl(r, 3, 64));
        float t45 = __fadd_rn(__shfl(r, 4, 64), __shfl(r, 5, 64));
        float t67 = __fadd_rn(__shfl(r, 6, 64), __shfl(r, 7, 64));
        float en  = __fadd_rn(__fadd_rn(t01, t23), __fadd_rn(t45, t67));

        // sinit: exact sequential fp64 order (0+d0)+d1+...+d63.
        double dq = (double)v * (double)v;
        double acc = __shfl(dq, 0, 64);
#pragma unroll
        for (int d2 = 1; d2 < 64; ++d2)
            acc = acc + __shfl(dq, d2, 64);

        if (lane == 0) {
            enorm[k] = en;
            sinit[k] = (float)acc;
            counts[k] = 0u;
        }
    }
    if (blockIdx.x == 0 && threadIdx.x == 0) { *sse = 0.f; *rcnt = 0u; }
}

// ---------------------------------------------------------------------------
// Screen (r5 structure, 66 us verified): LDS-staged codebook chunks
// (double-buffered, swizzled), 12-MFMA hi/lo scheme, in-register top-2,
// packed winner to win[]. sinit staged to LDS once.
// ---------------------------------------------------------------------------
#define MFMA(A, B, C) __builtin_amdgcn_mfma_f32_16x16x32_bf16(A, B, C, 0, 0, 0)

__device__ __forceinline__ void tile_step(
    int code, const bf16x8 (&Ah)[2][2], const bf16x8 (&Al)[2][2],
    bf16x8 H0, bf16x8 H1, bf16x8 L0, bf16x8 L1, float si,
    float (&m1)[8], float (&m2)[8], int (&i1)[8]) {
    f32x4 C0 = {si, si, si, si};
    f32x4 C1 = {si, si, si, si};
    C0 = MFMA(Ah[0][0], H0, C0); C0 = MFMA(Ah[0][1], H1, C0);
    C0 = MFMA(Ah[0][0], L0, C0); C0 = MFMA(Ah[0][1], L1, C0);
    C0 = MFMA(Al[0][0], H0, C0); C0 = MFMA(Al[0][1], H1, C0);
    C1 = MFMA(Ah[1][0], H0, C1); C1 = MFMA(Ah[1][1], H1, C1);
    C1 = MFMA(Ah[1][0], L0, C1); C1 = MFMA(Ah[1][1], L1, C1);
    C1 = MFMA(Al[1][0], H0, C1); C1 = MFMA(Al[1][1], H1, C1);
#pragma unroll
    for (int r = 0; r < 4; ++r) {
        {
            float c = C0[r];
            // med3(m1,m2,c) == min(m2, max(m1,c)) given m1<=m2 (exact select)
            m2[r] = __builtin_amdgcn_fmed3f(m1[r], m2[r], c);
            bool lt = c < m1[r];
            i1[r] = lt ? code : i1[r];
            m1[r] = fminf(m1[r], c);
        }
        {
            float c = C1[r];
            m2[4 + r] = __builtin_amdgcn_fmed3f(m1[4 + r], m2[4 + r], c);
            bool lt = c < m1[4 + r];
            i1[4 + r] = lt ? code : i1[4 + r];
            m1[4 + r] = fminf(m1[4 + r], c);
        }
    }
}

__global__ __launch_bounds__(256, 4)
void vq_screen(const float* __restrict__ x,
               const float* __restrict__ sinit,
               const short* __restrict__ w_hi,
               const short* __restrict__ w_lo,
               int* __restrict__ win) {
    const int tid  = threadIdx.x;
    const int lane = tid & 63;
    const int wv   = __builtin_amdgcn_readfirstlane(tid >> 6);
    const int quad = lane >> 4;
    const int col  = lane & 15;
    const int tokWave = blockIdx.x * 128 + wv * 32;

    // [buf][hi/lo][64 codes * 64 dims] = 32 KB
    __shared__ short sB[2][2][4096];
    __shared__ float sS[1024];   // sinit staged once (4 KB)

    bf16x8 Ah[2][2], Al[2][2];
#pragma unroll
    for (int mt = 0; mt < 2; ++mt) {
#pragma unroll
        for (int ks = 0; ks < 2; ++ks) {
            const float4* ap = (const float4*)(x + (size_t)(tokWave + mt * 16 + col) * D
                                               + ks * 32 + quad * 8);
            float4 u0 = ap[0], u1 = ap[1];
            float f[8] = {u0.x, u0.y, u0.z, u0.w, u1.x, u1.y, u1.z, u1.w};
            bf16x8 h, l;
#pragma unroll
            for (int j = 0; j < 8; ++j) {
                float v = -2.0f * f[j];
                short hi = bf16_trunc(v);
                float res = v - bf16_up(hi);
                h[j] = hi;
                l[j] = bf16_trunc(res);
            }
            Ah[mt][ks] = h;
            Al[mt][ks] = l;
        }
    }

    float m1[8], m2[8];
    int   i1[8];
#pragma unroll
    for (int s = 0; s < 8; ++s) { m1[s] = INFINITY; m2[s] = INFINITY; i1[s] = 0; }

    // Staging geometry: chunk = 64 codes = 8192 B per array (hi, lo).
    const int  p0 = tid * 16;
    const int  p1 = p0 + 4096;
    const char* gh = (const char*)w_hi;
    const char* gl = (const char*)w_lo;

    // Initial stage: chunk 0 -> buf 0, plus sinit -> LDS.
    {
        float4 g0 = *(const float4*)(gh + p0);
        float4 g1 = *(const float4*)(gh + p1);
        float4 g2 = *(const float4*)(gl + p0);
        float4 g3 = *(const float4*)(gl + p1);
        float4 s4 = *(const float4*)(sinit + tid * 4);
        char* lh = (char*)&sB[0][0][0];
        char* ll = (char*)&sB[0][1][0];
        *(float4*)(lh + SWZ(p0)) = g0;
        *(float4*)(lh + SWZ(p1)) = g1;
        *(float4*)(ll + SWZ(p0)) = g2;
        *(float4*)(ll + SWZ(p1)) = g3;
        *(float4*)(&sS[tid * 4]) = s4;
    }
    __syncthreads();

    for (int c = 0; c < 16; ++c) {
        const int buf = c & 1;
        const bool pf = (c < 15);
        float4 g0, g1, g2, g3;
        if (pf) {
            const size_t cb = (size_t)(c + 1) * 8192;
            g0 = *(const float4*)(gh + cb + p0);
            g1 = *(const float4*)(gh + cb + p1);
            g2 = *(const float4*)(gl + cb + p0);
            g3 = *(const float4*)(gl + cb + p1);
        }

        const char* lh = (const char*)&sB[buf][0][0];
        const char* ll = (const char*)&sB[buf][1][0];
#pragma unroll
        for (int tl = 0; tl < 4; ++tl) {
            const int r_ = tl * 16 + col;          // code row within chunk
            const int b0 = r_ * 128 + quad * 16;
            const int b1 = b0 + 64;
            bf16x8 H0 = *(const bf16x8*)(lh + SWZ(b0));
            bf16x8 H1 = *(const bf16x8*)(lh + SWZ(b1));
            bf16x8 L0 = *(const bf16x8*)(ll + SWZ(b0));
            bf16x8 L1 = *(const bf16x8*)(ll + SWZ(b1));
            const int tile = c * 4 + tl;
            const float si = sS[tile * 16 + col];
            tile_step(tile * 16 + col, Ah, Al, H0, H1, L0, L1, si, m1, m2, i1);
        }

        if (pf) {
            char* dh = (char*)&sB[buf ^ 1][0][0];
            char* dl = (char*)&sB[buf ^ 1][1][0];
            *(float4*)(dh + SWZ(p0)) = g0;
            *(float4*)(dh + SWZ(p1)) = g1;
            *(float4*)(dl + SWZ(p0)) = g2;
            *(float4*)(dl + SWZ(p1)) = g3;
        }
        __syncthreads();
    }

#pragma unroll
    for (int s = 0; s < 8; ++s) {
#pragma unroll
        for (int msk = 1; msk <= 8; msk <<= 1) {
            float om1 = __shfl_xor(m1[s], msk, 64);
            int   oi1 = __shfl_xor(i1[s], msk, 64);
            float om2 = __shfl_xor(m2[s], msk, 64);
            float nm2 = fminf(fmaxf(m1[s], om1), fminf(m2[s], om2));
            bool  take = om1 < m1[s];
            m1[s] = take ? om1 : m1[s];
            i1[s] = take ? oi1 : i1[s];
            m2[s] = nm2;
        }
    }

    if (col == 0) {
#pragma unroll
        for (int s = 0; s < 8; ++s) {
            int tl = (s >> 2) * 16 + quad * 4 + (s & 3);
            bool resc = (m2[s] <= m1[s] + W_WINDOW);
            win[tokWave + tl] = resc ? (i1[s] | 0x80000000) : i1[s];
        }
    }
}
#undef MFMA

// ---------------------------------------------------------------------------
// Epilogue (EXACT r5 structure, proven <66 us inside the 249-us total).
// Phase A (1 thread/token): unpack win[], rescue->rlist, else counts+idx.
// Phase B (16 lanes/token): coalesced gather+copy+SSE, 512 blocks.
// ---------------------------------------------------------------------------
__global__ __launch_bounds__(256, 4)
void vq_epi(const float* __restrict__ x,
            const float* __restrict__ w,
            const int* __restrict__ win,
            float* __restrict__ out,
            unsigned* __restrict__ counts,
            float* __restrict__ sse,
            int* __restrict__ rlist,
            unsigned* __restrict__ rcnt) {
    __shared__ int smw[256];
    const int t = blockIdx.x * 256 + threadIdx.x;

    const int wi = win[t];
    if (wi < 0) {
        unsigned u = atomicAdd(rcnt, 1u);
        rlist[u] = t;
        smw[threadIdx.x] = -1;
    } else {
        atomicAdd(&counts[wi], 1u);
        out[OUT_IDX + t] = (float)wi;
        smw[threadIdx.x] = wi;
    }
    __syncthreads();

    // Phase B: coalesced copy + SSE
    const int lane = threadIdx.x & 63;
    const int wvi  = threadIdx.x >> 6;
    const int sub  = lane >> 4;         // token within 4-token pass
    const int i    = lane & 15;         // float4 index within 64-float row
    float err = 0.f;
#pragma unroll
    for (int p = 0; p < 16; ++p) {
        const int tl  = wvi * 64 + p * 4 + sub;          // local token 0..255
        const int tok = blockIdx.x * 256 + tl;
        const int wi2 = smw[tl];
        if (wi2 >= 0) {
            float4 q  = ((const float4*)(w + (size_t)wi2 * D))[i];
            float4 xv = ((const float4*)(x + (size_t)tok * D))[i];
            float e0 = q.x - xv.x, e1 = q.y - xv.y;
            float e2 = q.z - xv.z, e3 = q.w - xv.w;
            err = fmaf(e0, e0, err);
            err = fmaf(e1, e1, err);
            err = fmaf(e2, e2, err);
            err = fmaf(e3, e3, err);
            ((float4*)(out + (size_t)tok * D))[i] = q;
        }
    }
#pragma unroll
    for (int o = 32; o > 0; o >>= 1) err += __shfl_down(err, o, 64);
    if (lane == 0) atomicAdd(sse, err);
}

// ---------------------------------------------------------------------------
// Rescue v3 (EXACT r5 version, proven <66 us inside the 249-us total; the
// r8 2-way interleave regressed it to a measured 92 via SGPR=112 scalar-
// cache thrash and is NOT applied). 512 threads = 8 waves (2 waves/SIMD ->
// 256-VGPR budget), wave wv scans codes [wv*128, wv*128+128) ascending with
// the np-exact fp32 chain, wave-uniform scalar w loads. LDS first-min
// combine over 8 chunks ascending == np.argmin.
// ---------------------------------------------------------------------------
#define XR(d) ((d) < 16 ? xa[(d) & 15] : (d) < 32 ? xb[(d) & 15] \
              : (d) < 48 ? xc[(d) & 15] : xd[(d) & 15])

__global__ __launch_bounds__(512, 2)
void vq_rescue(const float* __restrict__ x,
               const float* __restrict__ w,
               const float* __restrict__ enorm,
               float* __restrict__ out,
               unsigned* __restrict__ counts,
               float* __restrict__ sse,
               const int* __restrict__ rlist,
               const unsigned* __restrict__ rcnt) {
    const int lane = threadIdx.x & 63;
    const int wv   = __builtin_amdgcn_readfirstlane(threadIdx.x >> 6);  // 0..7
    const unsigned n = *rcnt;

    __shared__ float sd[8][64];
    __shared__ int   si[8][64];

    for (unsigned g = blockIdx.x; g * 64u < n; g += 256u) {
        const unsigned slot = g * 64u + (unsigned)lane;
        const bool valid = slot < n;
        const int t = valid ? rlist[slot] : 0;

        const vf16* xp = (const vf16*)(x + (size_t)t * D);
        vf16 xa = xp[0], xb = xp[1], xc = xp[2], xd = xp[3];

        // Sx np-exact (8 accumulators, ascending blocks, pairwise tail).
        float Sx;
        {
            float r0, r1, r2, r3, r4, r5, r6, r7;
#define SQ(n) __fmul_rn(XR(n), XR(n))
            r0 = SQ(0); r1 = SQ(1); r2 = SQ(2); r3 = SQ(3);
            r4 = SQ(4); r5 = SQ(5); r6 = SQ(6); r7 = SQ(7);
#define ACC8(i)                                                           \
            r0 = __fadd_rn(r0, SQ(8*(i)+0)); r1 = __fadd_rn(r1, SQ(8*(i)+1)); \
            r2 = __fadd_rn(r2, SQ(8*(i)+2)); r3 = __fadd_rn(r3, SQ(8*(i)+3)); \
            r4 = __fadd_rn(r4, SQ(8*(i)+4)); r5 = __fadd_rn(r5, SQ(8*(i)+5)); \
            r6 = __fadd_rn(r6, SQ(8*(i)+6)); r7 = __fadd_rn(r7, SQ(8*(i)+7));
            ACC8(1) ACC8(2) ACC8(3) ACC8(4) ACC8(5) ACC8(6) ACC8(7)
            Sx = __fadd_rn(
                __fadd_rn(__fadd_rn(r0, r1), __fadd_rn(r2, r3)),
                __fadd_rn(__fadd_rn(r4, r5), __fadd_rn(r6, r7)));
#undef ACC8
#undef SQ
        }

        // np-exact scan of this wave's 128-code chunk (c ascending).
        float best = INFINITY;
        int   bidx = 0x7fffffff;
        const int c0 = wv * 128;
        for (int cc = 0; cc < 128; ++cc) {
            const int c = c0 + cc;
            const float* __restrict__ wr = w + (size_t)c * D;  // wave-uniform
            float a = 0.f;
#pragma unroll
            for (int d = 0; d < D; ++d) a = __fmaf_rn(wr[d], XR(d), a);
            float dist = __fsub_rn(__fadd_rn(Sx, enorm[c]), __fmul_rn(2.0f, a));
            bool lt = dist < best;  // strict <: first-min within chunk
            best = lt ? dist : best;
            bidx = lt ? c : bidx;
        }
        sd[wv][lane] = best;
        si[wv][lane] = bidx;
        __syncthreads();

        if (wv == 0) {
            float b  = sd[0][lane];
            int   bi = si[0][lane];
#pragma unroll
            for (int j = 1; j < 8; ++j) {
                float dj = sd[j][lane];
                bool  l  = dj < b;  // strict <: lower chunk (lower idx) wins ties
                b  = l ? dj : b;
                bi = l ? si[j][lane] : bi;
            }

            float err = 0.f;
            if (valid) {
                const float4* qr = (const float4*)(w + (size_t)bi * D);
                float4*       oq = (float4*)(out + (size_t)t * D);
#pragma unroll
                for (int i = 0; i < 16; ++i) {
                    float4 q = qr[i];
                    float e0 = q.x - XR(4 * i + 0);
                    float e1 = q.y - XR(4 * i + 1);
                    float e2 = q.z - XR(4 * i + 2);
                    float e3 = q.w - XR(4 * i + 3);
                    err = fmaf(e0, e0, err);
                    err = fmaf(e1, e1, err);
                    err = fmaf(e2, e2, err);
                    err = fmaf(e3, e3, err);
                    oq[i] = q;
                }
                out[OUT_IDX + t] = (float)bi;
                atomicAdd(&counts[bi], 1u);
            }
#pragma unroll
            for (int o = 32; o > 0; o >>= 1) err += __shfl_down(err, o, 64);
            if (lane == 0) atomicAdd(sse, err);
        }
        __syncthreads();
    }
}
#undef XR

// ---------------------------------------------------------------------------
__global__ void vq_fin(const unsigned* __restrict__ counts,
                       const float* __restrict__ sse,
                       float* __restrict__ out) {
    __shared__ float red[256];
    float s = 0.f;
    for (int k = threadIdx.x; k < K; k += 256) {
        float p = (float)counts[k] * (1.0f / (float)N_TOK);
        s += p * logf(p + 1e-10f);
    }
    red[threadIdx.x] = s;
    __syncthreads();
    for (int st = 128; st > 0; st >>= 1) {
        if (threadIdx.x < st) red[threadIdx.x] += red[threadIdx.x + st];
        __syncthreads();
    }
    if (threadIdx.x == 0) {
        out[OUT_PERP] = expf(-red[0]);
        out[OUT_LOSS] = 1.25f * (*sse) * (1.0f / 8388608.0f);  // (1+0.25)*MSE
    }
}

// ---------------------------------------------------------------------------
extern "C" void kernel_launch(void* const* d_in, const int* in_sizes, int n_in,
                              void* d_out, int out_size, void* d_ws, size_t ws_size,
                              hipStream_t stream) {
    const float* x = (const float*)d_in[0];  // [32,64,64,64] fp32
    const float* w = (const float*)d_in[1];  // [1024,64] fp32
    float* out = (float*)d_out;

    char* ws = (char*)d_ws;
    unsigned* counts = (unsigned*)(ws + 0);
    float*    enorm  = (float*)(ws + 4096);
    float*    sinit  = (float*)(ws + 8192);
    float*    sse    = (float*)(ws + 12288);
    unsigned* rcnt   = (unsigned*)(ws + 12292);
    short*    w_hi   = (short*)(ws + 16384);
    short*    w_lo   = (short*)(ws + 147456);
    int*      win    = (int*)(ws + 278528);
    int*      rlist  = (int*)(ws + 802816);

    vq_prep<<<64, 256, 0, stream>>>(w, enorm, sinit, w_hi, w_lo, counts, sse, rcnt);
    vq_screen<<<N_TOK / 128, 256, 0, stream>>>(x, sinit, w_hi, w_lo, win);
    vq_epi<<<N_TOK / 256, 256, 0, stream>>>(x, w, win, out, counts, sse, rlist, rcnt);
    vq_rescue<<<256, 512, 0, stream>>>(x, w, enorm, out, counts, sse, rlist, rcnt);
    vq_fin<<<1, 256, 0, stream>>>(counts, sse, out);
}

// Round 12
// 249.510 us; speedup vs baseline: 2.2509x; 1.1144x over previous
//
#include <hip/hip_runtime.h>
#include <math.h>

// Problem constants
#define N_TOK 131072   // 32*64*64 tokens
#define D     64       // embedding dim
#define K     1024     // codebook size

// Output layout (floats, concatenated in reference return order):
#define OUT_LOSS  8388608
#define OUT_IDX   8388609
#define OUT_PERP  8519681

// ws layout (bytes):
//   0        counts  u32[1024]
//   4096     enorm   f32[1024]  np-exact ||e||^2
//   8192     sinit   f32[1024]  fp64-accurate ||e||^2 (screen C-init)
//   12288    sse     f32
//   12292    rcnt    u32        rescue-list counter
//   16384    w_hi    s16[65536] bf16 hi split of w (128 KB)
//   147456   w_lo    s16[65536] bf16 lo split of w (128 KB)
//   278528   win     i32[131072] packed winner (bit31 = needs rescue)
//   802816   rlist   i32[131072] compacted rescue token ids

#define W_WINDOW 1e-4f

typedef short bf16x8 __attribute__((ext_vector_type(8)));
typedef float f32x4  __attribute__((ext_vector_type(4)));
typedef float vf16   __attribute__((ext_vector_type(16)));

// LDS byte-offset swizzle: XOR bits 4-6 with row bits (byte>>7)&7.
// Involution; applied on BOTH ds_write (staging) and ds_read (fragments).
#define SWZ(p) ((p) ^ ((((p) >> 7) & 7) << 4))

__device__ __forceinline__ short bf16_trunc(float f) {
    return (short)(__float_as_uint(f) >> 16);
}
__device__ __forceinline__ float bf16_up(short s) {
    return __uint_as_float(((unsigned)(unsigned short)s) << 16);
}

// ---------------------------------------------------------------------------
// prep v3. r11 counters unmasked prep-v2 as a 90-us kernel: the 63-deep
// sequential fp64 shfl chain (126 live bpermute halves vs 64 VGPRs) spilled
// ~6 MB to scratch (WRITE_SIZE 6.3 MB, VALUBusy 0.004%). v3: NO cross-lane
// ops. Phase 1 = coalesced lane=dim load, hi/lo split+store, row -> LDS.
// Phase 2 = thread t owns row t from LDS: r[j] accumulators in ascending-
// group order + pairwise tail == np_pairsum64 bit-exact; plain sequential
// double acc (d=0..63) == r0 sinit order. Independent per-thread chains,
// ~30 VGPRs, no spill. 8 blocks x 256 threads, 128 rows/block, 33 KB LDS.
// ---------------------------------------------------------------------------
__global__ __launch_bounds__(256, 4)
void vq_prep(const float* __restrict__ w,
             float* __restrict__ enorm,
             float* __restrict__ sinit,
             short* __restrict__ w_hi,
             short* __restrict__ w_lo,
             unsigned* __restrict__ counts,
             float* __restrict__ sse,
             unsigned* __restrict__ rcnt) {
    const int lane = threadIdx.x & 63;
    const int wv   = threadIdx.x >> 6;
    const int base = blockIdx.x * 128;           // 8 blocks x 128 rows

    __shared__ float xs[128][65];                // +1 pad: 2-way alias (free)

    // Phase 1: coalesced load / split / store, stage rows to LDS.
    for (int rr = 0; rr < 32; ++rr) {
        const int rloc = rr * 4 + wv;            // 0..127
        const int k = base + rloc;
        const float v = w[(size_t)k * D + lane]; // coalesced 256B/wave
        short hi = bf16_trunc(v);
        float res = v - bf16_up(hi);
        short lo = bf16_trunc(res);
        w_hi[(size_t)k * D + lane] = hi;         // coalesced 128B/wave
        w_lo[(size_t)k * D + lane] = lo;
        xs[rloc][lane] = v;
    }
    __syncthreads();

    // Phase 2: per-thread exact reductions from LDS (threads 0..127).
    if (threadIdx.x < 128) {
        const int k = base + threadIdx.x;
        const float* xr = &xs[threadIdx.x][0];
        float r[8];
        double acc = 0.0;
#pragma unroll
        for (int g = 0; g < 8; ++g) {
#pragma unroll
            for (int j = 0; j < 8; ++j) {
                const float v = xr[g * 8 + j];
                const float sq = __fmul_rn(v, v);
                r[j] = (g == 0) ? sq : __fadd_rn(r[j], sq);
                acc += (double)v * (double)v;    // sequential d ascending
            }
        }
        const float en = __fadd_rn(
            __fadd_rn(__fadd_rn(r[0], r[1]), __fadd_rn(r[2], r[3])),
            __fadd_rn(__fadd_rn(r[4], r[5]), __fadd_rn(r[6], r[7])));
        enorm[k] = en;
        sinit[k] = (float)acc;
        counts[k] = 0u;
    }
    if (blockIdx.x == 0 && threadIdx.x == 0) { *sse = 0.f; *rcnt = 0u; }
}

// ---------------------------------------------------------------------------
// Screen (r5 structure, 62 us / MfmaUtil 34% verified in r11): LDS-staged
// codebook chunks (double-buffered, swizzled), 12-MFMA hi/lo scheme,
// in-register top-2, packed winner to win[]. sinit staged to LDS once.
// ---------------------------------------------------------------------------
#define MFMA(A, B, C) __builtin_amdgcn_mfma_f32_16x16x32_bf16(A, B, C, 0, 0, 0)

__device__ __forceinline__ void tile_step(
    int code, const bf16x8 (&Ah)[2][2], const bf16x8 (&Al)[2][2],
    bf16x8 H0, bf16x8 H1, bf16x8 L0, bf16x8 L1, float si,
    float (&m1)[8], float (&m2)[8], int (&i1)[8]) {
    f32x4 C0 = {si, si, si, si};
    f32x4 C1 = {si, si, si, si};
    C0 = MFMA(Ah[0][0], H0, C0); C0 = MFMA(Ah[0][1], H1, C0);
    C0 = MFMA(Ah[0][0], L0, C0); C0 = MFMA(Ah[0][1], L1, C0);
    C0 = MFMA(Al[0][0], H0, C0); C0 = MFMA(Al[0][1], H1, C0);
    C1 = MFMA(Ah[1][0], H0, C1); C1 = MFMA(Ah[1][1], H1, C1);
    C1 = MFMA(Ah[1][0], L0, C1); C1 = MFMA(Ah[1][1], L1, C1);
    C1 = MFMA(Al[1][0], H0, C1); C1 = MFMA(Al[1][1], H1, C1);
#pragma unroll
    for (int r = 0; r < 4; ++r) {
        {
            float c = C0[r];
            // med3(m1,m2,c) == min(m2, max(m1,c)) given m1<=m2 (exact select)
            m2[r] = __builtin_amdgcn_fmed3f(m1[r], m2[r], c);
            bool lt = c < m1[r];
            i1[r] = lt ? code : i1[r];
            m1[r] = fminf(m1[r], c);
        }
        {
            float c = C1[r];
            m2[4 + r] = __builtin_amdgcn_fmed3f(m1[4 + r], m2[4 + r], c);
            bool lt = c < m1[4 + r];
            i1[4 + r] = lt ? code : i1[4 + r];
            m1[4 + r] = fminf(m1[4 + r], c);
        }
    }
}

__global__ __launch_bounds__(256, 4)
void vq_screen(const float* __restrict__ x,
               const float* __restrict__ sinit,
               const short* __restrict__ w_hi,
               const short* __restrict__ w_lo,
               int* __restrict__ win) {
    const int tid  = threadIdx.x;
    const int lane = tid & 63;
    const int wv   = __builtin_amdgcn_readfirstlane(tid >> 6);
    const int quad = lane >> 4;
    const int col  = lane & 15;
    const int tokWave = blockIdx.x * 128 + wv * 32;

    // [buf][hi/lo][64 codes * 64 dims] = 32 KB
    __shared__ short sB[2][2][4096];
    __shared__ float sS[1024];   // sinit staged once (4 KB)

    bf16x8 Ah[2][2], Al[2][2];
#pragma unroll
    for (int mt = 0; mt < 2; ++mt) {
#pragma unroll
        for (int ks = 0; ks < 2; ++ks) {
            const float4* ap = (const float4*)(x + (size_t)(tokWave + mt * 16 + col) * D
                                               + ks * 32 + quad * 8);
            float4 u0 = ap[0], u1 = ap[1];
            float f[8] = {u0.x, u0.y, u0.z, u0.w, u1.x, u1.y, u1.z, u1.w};
            bf16x8 h, l;
#pragma unroll
            for (int j = 0; j < 8; ++j) {
                float v = -2.0f * f[j];
                short hi = bf16_trunc(v);
                float res = v - bf16_up(hi);
                h[j] = hi;
                l[j] = bf16_trunc(res);
            }
            Ah[mt][ks] = h;
            Al[mt][ks] = l;
        }
    }

    float m1[8], m2[8];
    int   i1[8];
#pragma unroll
    for (int s = 0; s < 8; ++s) { m1[s] = INFINITY; m2[s] = INFINITY; i1[s] = 0; }

    // Staging geometry: chunk = 64 codes = 8192 B per array (hi, lo).
    const int  p0 = tid * 16;
    const int  p1 = p0 + 4096;
    const char* gh = (const char*)w_hi;
    const char* gl = (const char*)w_lo;

    // Initial stage: chunk 0 -> buf 0, plus sinit -> LDS.
    {
        float4 g0 = *(const float4*)(gh + p0);
        float4 g1 = *(const float4*)(gh + p1);
        float4 g2 = *(const float4*)(gl + p0);
        float4 g3 = *(const float4*)(gl + p1);
        float4 s4 = *(const float4*)(sinit + tid * 4);
        char* lh = (char*)&sB[0][0][0];
        char* ll = (char*)&sB[0][1][0];
        *(float4*)(lh + SWZ(p0)) = g0;
        *(float4*)(lh + SWZ(p1)) = g1;
        *(float4*)(ll + SWZ(p0)) = g2;
        *(float4*)(ll + SWZ(p1)) = g3;
        *(float4*)(&sS[tid * 4]) = s4;
    }
    __syncthreads();

    for (int c = 0; c < 16; ++c) {
        const int buf = c & 1;
        const bool pf = (c < 15);
        float4 g0, g1, g2, g3;
        if (pf) {
            const size_t cb = (size_t)(c + 1) * 8192;
            g0 = *(const float4*)(gh + cb + p0);
            g1 = *(const float4*)(gh + cb + p1);
            g2 = *(const float4*)(gl + cb + p0);
            g3 = *(const float4*)(gl + cb + p1);
        }

        const char* lh = (const char*)&sB[buf][0][0];
        const char* ll = (const char*)&sB[buf][1][0];
#pragma unroll
        for (int tl = 0; tl < 4; ++tl) {
            const int r_ = tl * 16 + col;          // code row within chunk
            const int b0 = r_ * 128 + quad * 16;
            const int b1 = b0 + 64;
            bf16x8 H0 = *(const bf16x8*)(lh + SWZ(b0));
            bf16x8 H1 = *(const bf16x8*)(lh + SWZ(b1));
            bf16x8 L0 = *(const bf16x8*)(ll + SWZ(b0));
            bf16x8 L1 = *(const bf16x8*)(ll + SWZ(b1));
            const int tile = c * 4 + tl;
            const float si = sS[tile * 16 + col];
            tile_step(tile * 16 + col, Ah, Al, H0, H1, L0, L1, si, m1, m2, i1);
        }

        if (pf) {
            char* dh = (char*)&sB[buf ^ 1][0][0];
            char* dl = (char*)&sB[buf ^ 1][1][0];
            *(float4*)(dh + SWZ(p0)) = g0;
            *(float4*)(dh + SWZ(p1)) = g1;
            *(float4*)(dl + SWZ(p0)) = g2;
            *(float4*)(dl + SWZ(p1)) = g3;
        }
        __syncthreads();
    }

#pragma unroll
    for (int s = 0; s < 8; ++s) {
#pragma unroll
        for (int msk = 1; msk <= 8; msk <<= 1) {
            float om1 = __shfl_xor(m1[s], msk, 64);
            int   oi1 = __shfl_xor(i1[s], msk, 64);
            float om2 = __shfl_xor(m2[s], msk, 64);
            float nm2 = fminf(fmaxf(m1[s], om1), fminf(m2[s], om2));
            bool  take = om1 < m1[s];
            m1[s] = take ? om1 : m1[s];
            i1[s] = take ? oi1 : i1[s];
            m2[s] = nm2;
        }
    }

    if (col == 0) {
#pragma unroll
        for (int s = 0; s < 8; ++s) {
            int tl = (s >> 2) * 16 + quad * 4 + (s & 3);
            bool resc = (m2[s] <= m1[s] + W_WINDOW);
            win[tokWave + tl] = resc ? (i1[s] | 0x80000000) : i1[s];
        }
    }
}
#undef MFMA

// ---------------------------------------------------------------------------
// Epilogue (EXACT r5 structure). Phase A (1 thread/token): unpack win[],
// rescue->rlist, else counts+idx. Phase B (16 lanes/token): coalesced
// gather+copy+SSE, 512 blocks.
// ---------------------------------------------------------------------------
__global__ __launch_bounds__(256, 4)
void vq_epi(const float* __restrict__ x,
            const float* __restrict__ w,
            const int* __restrict__ win,
            float* __restrict__ out,
            unsigned* __restrict__ counts,
            float* __restrict__ sse,
            int* __restrict__ rlist,
            unsigned* __restrict__ rcnt) {
    __shared__ int smw[256];
    const int t = blockIdx.x * 256 + threadIdx.x;

    const int wi = win[t];
    if (wi < 0) {
        unsigned u = atomicAdd(rcnt, 1u);
        rlist[u] = t;
        smw[threadIdx.x] = -1;
    } else {
        atomicAdd(&counts[wi], 1u);
        out[OUT_IDX + t] = (float)wi;
        smw[threadIdx.x] = wi;
    }
    __syncthreads();

    // Phase B: coalesced copy + SSE
    const int lane = threadIdx.x & 63;
    const int wvi  = threadIdx.x >> 6;
    const int sub  = lane >> 4;         // token within 4-token pass
    const int i    = lane & 15;         // float4 index within 64-float row
    float err = 0.f;
#pragma unroll
    for (int p = 0; p < 16; ++p) {
        const int tl  = wvi * 64 + p * 4 + sub;          // local token 0..255
        const int tok = blockIdx.x * 256 + tl;
        const int wi2 = smw[tl];
        if (wi2 >= 0) {
            float4 q  = ((const float4*)(w + (size_t)wi2 * D))[i];
            float4 xv = ((const float4*)(x + (size_t)tok * D))[i];
            float e0 = q.x - xv.x, e1 = q.y - xv.y;
            float e2 = q.z - xv.z, e3 = q.w - xv.w;
            err = fmaf(e0, e0, err);
            err = fmaf(e1, e1, err);
            err = fmaf(e2, e2, err);
            err = fmaf(e3, e3, err);
            ((float4*)(out + (size_t)tok * D))[i] = q;
        }
    }
#pragma unroll
    for (int o = 32; o > 0; o >>= 1) err += __shfl_down(err, o, 64);
    if (lane == 0) atomicAdd(sse, err);
}

// ---------------------------------------------------------------------------
// Rescue v3 (EXACT r5 version). 512 threads = 8 waves (2 waves/SIMD ->
// 256-VGPR budget), wave wv scans codes [wv*128, wv*128+128) ascending with
// the np-exact fp32 chain, wave-uniform scalar w loads. LDS first-min
// combine over 8 chunks ascending == np.argmin.
// ---------------------------------------------------------------------------
#define XR(d) ((d) < 16 ? xa[(d) & 15] : (d) < 32 ? xb[(d) & 15] \
              : (d) < 48 ? xc[(d) & 15] : xd[(d) & 15])

__global__ __launch_bounds__(512, 2)
void vq_rescue(const float* __restrict__ x,
               const float* __restrict__ w,
               const float* __restrict__ enorm,
               float* __restrict__ out,
               unsigned* __restrict__ counts,
               float* __restrict__ sse,
               const int* __restrict__ rlist,
               const unsigned* __restrict__ rcnt) {
    const int lane = threadIdx.x & 63;
    const int wv   = __builtin_amdgcn_readfirstlane(threadIdx.x >> 6);  // 0..7
    const unsigned n = *rcnt;

    __shared__ float sd[8][64];
    __shared__ int   si[8][64];

    for (unsigned g = blockIdx.x; g * 64u < n; g += 256u) {
        const unsigned slot = g * 64u + (unsigned)lane;
        const bool valid = slot < n;
        const int t = valid ? rlist[slot] : 0;

        const vf16* xp = (const vf16*)(x + (size_t)t * D);
        vf16 xa = xp[0], xb = xp[1], xc = xp[2], xd = xp[3];

        // Sx np-exact (8 accumulators, ascending blocks, pairwise tail).
        float Sx;
        {
            float r0, r1, r2, r3, r4, r5, r6, r7;
#define SQ(n) __fmul_rn(XR(n), XR(n))
            r0 = SQ(0); r1 = SQ(1); r2 = SQ(2); r3 = SQ(3);
            r4 = SQ(4); r5 = SQ(5); r6 = SQ(6); r7 = SQ(7);
#define ACC8(i)                                                           \
            r0 = __fadd_rn(r0, SQ(8*(i)+0)); r1 = __fadd_rn(r1, SQ(8*(i)+1)); \
            r2 = __fadd_rn(r2, SQ(8*(i)+2)); r3 = __fadd_rn(r3, SQ(8*(i)+3)); \
            r4 = __fadd_rn(r4, SQ(8*(i)+4)); r5 = __fadd_rn(r5, SQ(8*(i)+5)); \
            r6 = __fadd_rn(r6, SQ(8*(i)+6)); r7 = __fadd_rn(r7, SQ(8*(i)+7));
            ACC8(1) ACC8(2) ACC8(3) ACC8(4) ACC8(5) ACC8(6) ACC8(7)
            Sx = __fadd_rn(
                __fadd_rn(__fadd_rn(r0, r1), __fadd_rn(r2, r3)),
                __fadd_rn(__fadd_rn(r4, r5), __fadd_rn(r6, r7)));
#undef ACC8
#undef SQ
        }

        // np-exact scan of this wave's 128-code chunk (c ascending).
        float best = INFINITY;
        int   bidx = 0x7fffffff;
        const int c0 = wv * 128;
        for (int cc = 0; cc < 128; ++cc) {
            const int c = c0 + cc;
            const float* __restrict__ wr = w + (size_t)c * D;  // wave-uniform
            float a = 0.f;
#pragma unroll
            for (int d = 0; d < D; ++d) a = __fmaf_rn(wr[d], XR(d), a);
            float dist = __fsub_rn(__fadd_rn(Sx, enorm[c]), __fmul_rn(2.0f, a));
            bool lt = dist < best;  // strict <: first-min within chunk
            best = lt ? dist : best;
            bidx = lt ? c : bidx;
        }
        sd[wv][lane] = best;
        si[wv][lane] = bidx;
        __syncthreads();

        if (wv == 0) {
            float b  = sd[0][lane];
            int   bi = si[0][lane];
#pragma unroll
            for (int j = 1; j < 8; ++j) {
                float dj = sd[j][lane];
                bool  l  = dj < b;  // strict <: lower chunk (lower idx) wins ties
                b  = l ? dj : b;
                bi = l ? si[j][lane] : bi;
            }

            float err = 0.f;
            if (valid) {
                const float4* qr = (const float4*)(w + (size_t)bi * D);
                float4*       oq = (float4*)(out + (size_t)t * D);
#pragma unroll
                for (int i = 0; i < 16; ++i) {
                    float4 q = qr[i];
                    float e0 = q.x - XR(4 * i + 0);
                    float e1 = q.y - XR(4 * i + 1);
                    float e2 = q.z - XR(4 * i + 2);
                    float e3 = q.w - XR(4 * i + 3);
                    err = fmaf(e0, e0, err);
                    err = fmaf(e1, e1, err);
                    err = fmaf(e2, e2, err);
                    err = fmaf(e3, e3, err);
                    oq[i] = q;
                }
                out[OUT_IDX + t] = (float)bi;
                atomicAdd(&counts[bi], 1u);
            }
#pragma unroll
            for (int o = 32; o > 0; o >>= 1) err += __shfl_down(err, o, 64);
            if (lane == 0) atomicAdd(sse, err);
        }
        __syncthreads();
    }
}
#undef XR

// ---------------------------------------------------------------------------
__global__ void vq_fin(const unsigned* __restrict__ counts,
                       const float* __restrict__ sse,
                       float* __restrict__ out) {
    __shared__ float red[256];
    float s = 0.f;
    for (int k = threadIdx.x; k < K; k += 256) {
        float p = (float)counts[k] * (1.0f / (float)N_TOK);
        s += p * logf(p + 1e-10f);
    }
    red[threadIdx.x] = s;
    __syncthreads();
    for (int st = 128; st > 0; st >>= 1) {
        if (threadIdx.x < st) red[threadIdx.x] += red[threadIdx.x + st];
        __syncthreads();
    }
    if (threadIdx.x == 0) {
        out[OUT_PERP] = expf(-red[0]);
        out[OUT_LOSS] = 1.25f * (*sse) * (1.0f / 8388608.0f);  // (1+0.25)*MSE
    }
}

// ---------------------------------------------------------------------------
extern "C" void kernel_launch(void* const* d_in, const int* in_sizes, int n_in,
                              void* d_out, int out_size, void* d_ws, size_t ws_size,
                              hipStream_t stream) {
    const float* x = (const float*)d_in[0];  // [32,64,64,64] fp32
    const float* w = (const float*)d_in[1];  // [1024,64] fp32
    float* out = (float*)d_out;

    char* ws = (char*)d_ws;
    unsigned* counts = (unsigned*)(ws + 0);
    float*    enorm  = (float*)(ws + 4096);
    float*    sinit  = (float*)(ws + 8192);
    float*    sse    = (float*)(ws + 12288);
    unsigned* rcnt   = (unsigned*)(ws + 12292);
    short*    w_hi   = (short*)(ws + 16384);
    short*    w_lo   = (short*)(ws + 147456);
    int*      win    = (int*)(ws + 278528);
    int*      rlist  = (int*)(ws + 802816);

    vq_prep<<<8, 256, 0, stream>>>(w, enorm, sinit, w_hi, w_lo, counts, sse, rcnt);
    vq_screen<<<N_TOK / 128, 256, 0, stream>>>(x, sinit, w_hi, w_lo, win);
    vq_epi<<<N_TOK / 256, 256, 0, stream>>>(x, w, win, out, counts, sse, rlist, rcnt);
    vq_rescue<<<256, 512, 0, stream>>>(x, w, enorm, out, counts, sse, rlist, rcnt);
    vq_fin<<<1, 256, 0, stream>>>(counts, sse, out);
}